// Round 4
// baseline (210.143 us; speedup 1.0000x reference)
//
#include <hip/hip_runtime.h>
#include <hip/hip_bf16.h>

typedef __hip_bfloat16 bf16;
typedef unsigned short ushort8v __attribute__((ext_vector_type(8)));
typedef short  s16x4  __attribute__((ext_vector_type(4)));
typedef short  bf16x8 __attribute__((ext_vector_type(8)));   // 8 bf16 (4 VGPRs)
typedef float  f32x4  __attribute__((ext_vector_type(4)));

#define HW 4096
#define IMG_W 64

__device__ __forceinline__ float bfbits2f(unsigned short u) {
    return __uint_as_float(((unsigned int)u) << 16);
}
__device__ __forceinline__ short f2bs(float f) {
    bf16 h = __float2bfloat16(f);
    return *reinterpret_cast<short*>(&h);
}

// async global->LDS, 16B per lane (wave-uniform LDS base + lane*16 scatter).
__device__ __forceinline__ void gl_lds16(const void* g, void* s) {
    __builtin_amdgcn_global_load_lds(
        (const __attribute__((address_space(1))) unsigned int*)g,
        (__attribute__((address_space(3))) unsigned int*)s, 16, 0, 0);
}

// ---------------------------------------------------------------------------
// pack_input: concat(gar,cond) fp32 [512][4096] -> inp_t bf16 in chunked
// layout [cc=16][pix=4096][32ch]  (64 B per pixel per cc-chunk).
// ---------------------------------------------------------------------------
__device__ void pack_input_dev(const float* __restrict__ gar,
                               const float* __restrict__ cond,
                               short* __restrict__ outp, int bx2, float* tile)
{
    int bx = bx2 & 127;                // px tile (128)
    int by = bx2 >> 7;                 // ch tile (16) == cc chunk
    int tx = threadIdx.x & 31;
    int ty = threadIdx.x >> 5;
#pragma unroll
    for (int i = 0; i < 4; ++i) {
        int c = by * 32 + ty + i * 8;
        const float* src = (c < 256) ? (gar + (size_t)c * HW)
                                     : (cond + (size_t)(c - 256) * HW);
        tile[(ty + i * 8) * 33 + tx] = src[bx * 32 + tx];
    }
    __syncthreads();
#pragma unroll
    for (int i = 0; i < 4; ++i) {
        int p = bx * 32 + ty + i * 8;
        outp[((size_t)by * 4096 + p) * 32 + tx] = f2bs(tile[tx * 33 + ty + i * 8]);
    }
}

// ---------------------------------------------------------------------------
// pack_w: W fp32 [G][CREAL][CIN][3][3] -> bf16 blocks.
// COAL=false (conv2-4): [g][nt][cc][tap 9][q 4][oc BN][8 ic]   (old layout)
// COAL=true  (conv1)  : [g][nt][cc][tap 9][oc BN][q 4][8 ic]   -> a wave's
//   64-lane weight-fragment load is one contiguous 1 KB span.
// BLKB = 9*4*BN*16 bytes either way.
// ---------------------------------------------------------------------------
template<int CIN, int CREAL, int BN, int NT, bool COAL>
__device__ void pack_w_dev(const float* __restrict__ wgt, char* __restrict__ wp,
                           int bx, short* sT)
{
    constexpr int NCC  = CIN / 32;
    constexpr int BLKB = 9 * 4 * BN * 16;

    const int t  = threadIdx.x;
    const int cc = bx % NCC;
    const int nt = (bx / NCC) % NT;
    const int g  = bx / (NT * NCC);

    for (int i = t; i < BLKB / 8; i += 256)
        reinterpret_cast<s16x4*>(sT)[i] = s16x4{0, 0, 0, 0};
    __syncthreads();

    int ocmax = CREAL - nt * BN; if (ocmax > BN) ocmax = BN;
    const size_t base = ((size_t)(g * CREAL + nt * BN) * CIN + cc * 32) * 9;
    for (int i = t; i < ocmax * 288; i += 256) {
        int oc = i / 288;
        int r  = i % 288;                      // ic*9 + tap
        int ic = r / 9, tap = r % 9;
        size_t idx;
        if (COAL) idx = (size_t)(((tap * BN + oc) * 4 + (ic >> 3)) * 8 + (ic & 7));
        else      idx = (size_t)(((tap * 4 + (ic >> 3)) * BN + oc) * 8 + (ic & 7));
        sT[idx] = f2bs(wgt[base + (size_t)oc * CIN * 9 + r]);
    }
    __syncthreads();

    const s16x4* src = reinterpret_cast<const s16x4*>(sT);
    s16x4* dst = reinterpret_cast<s16x4*>(wp + (size_t)bx * BLKB);
    for (int i = t; i < BLKB / 8; i += 256)
        dst[i] = src[i];
}

// All packing in one launch (block-range dispatch; branch is block-uniform).
__global__ __launch_bounds__(256)
void pack_all(const float* __restrict__ gar, const float* __restrict__ cond,
              const float* __restrict__ W1, const float* __restrict__ W2,
              const float* __restrict__ W3, const float* __restrict__ W4,
              short* inp_t, char* W1p, char* W2p, char* W3p, char* W4p)
{
    __shared__ __align__(16) short sbuf[9 * 4 * 64 * 8];   // 36864 B
    int bx = blockIdx.x;
    if (bx < 256)      pack_w_dev<512, 128, 64, 2, true >(W1, W1p, bx,       sbuf);
    else if (bx < 288) pack_w_dev<128,  64, 64, 1, false>(W2, W2p, bx - 256, sbuf);
    else if (bx < 304) pack_w_dev< 64,  32, 32, 1, false>(W3, W3p, bx - 288, sbuf);
    else if (bx < 312) pack_w_dev< 32,  18, 32, 1, false>(W4, W4p, bx - 304, sbuf);
    else pack_input_dev(gar, cond, inp_t, bx - 312, (float*)sbuf);
}

// ---------------------------------------------------------------------------
// Implicit-GEMM 3x3 SAME conv, bf16 MFMA 16x16x32, conflict-free LDS.
// (old template — still used for conv2/3/4; input layout [pix][ICP])
// ---------------------------------------------------------------------------
template<int ICP, int CREAL, int BN, int ROWS, int OF, int NT, int NW, int PIPE,
         bool PIXMAJ_OUT, bool LEAKY, bool OUT_F32>
__global__ __launch_bounds__(NW * 64, 2)
void conv_mfma(const short* __restrict__ inp, const char* __restrict__ wp,
               const float* __restrict__ bias, void* __restrict__ outv)
{
    constexpr int NCC  = ICP / 32;
    constexpr int HALO = ROWS + 2;
    constexpr int NPT  = 4096 / (ROWS * 64);
    constexpr int BLKB = 9 * 4 * BN * 16;
    constexpr int RNDS = BLKB / 1024;
    constexpr int NBUF = (PIPE && NCC > 1) ? 2 : 1;
    constexpr int SMAX = (HALO + NW - 1) / NW;

    __shared__ __align__(16) short sA[HALO][4][68][8];
    __shared__ __align__(16) char  sBraw[NBUF][BLKB];

    const int b  = blockIdx.x;
    const int g  = b & 7;                     // XCD swizzle: group per XCD
    const int r_ = b >> 3;
    const int pt = r_ % NPT;
    const int nt = r_ / NPT;
    const int r0 = pt * ROWS;

    const int t    = threadIdx.x;
    const int wave = t >> 6, lane = t & 63;
    const int l15  = lane & 15, quad = lane >> 4;

    int row_l, ocw;
    if (NW == 8) {
        if (ROWS == 4) { row_l = wave >> 1; ocw = (wave & 1) * (BN / 2); }
        else           { row_l = wave >> 2; ocw = (wave & 3) * (BN / 4); }
    } else {
        row_l = (ROWS == 4) ? wave : (wave & 1);
        ocw   = (ROWS == 4) ? 0 : (wave >> 1) * (BN / 2);
    }

    const size_t gpix = (ICP == 512) ? 0 : ((size_t)g * 4096);
    const char*  wb   = wp + (size_t)((g * NT + nt) * NCC) * BLKB;

    // sA staging: thread -> (col, row-slice); rows j = r2, r2+NW, ...
    const int acol = t & 63;
    const int r2   = t >> 6;

    bf16x8 pre[SMAX][4];

    auto stageA_load = [&](int cc) {
#pragma unroll
        for (int s = 0; s < SMAX; ++s) {
            int j = r2 + s * NW;
            if (j < HALO) {
                int gy = r0 - 1 + j;
                if (gy >= 0 && gy < 64) {
                    const short* sp = inp + ((gpix + gy * 64 + acol) * ICP + cc * 32);
#pragma unroll
                    for (int q = 0; q < 4; ++q)
                        pre[s][q] = *reinterpret_cast<const bf16x8*>(sp + q * 8);
                } else {
#pragma unroll
                    for (int q = 0; q < 4; ++q)
                        pre[s][q] = bf16x8{0, 0, 0, 0, 0, 0, 0, 0};
                }
            }
        }
    };
    auto stageA_write = [&]() {
#pragma unroll
        for (int s = 0; s < SMAX; ++s) {
            int j = r2 + s * NW;
            if (j < HALO) {
#pragma unroll
                for (int q = 0; q < 4; ++q)
                    *reinterpret_cast<bf16x8*>(&sA[j][q][acol + 1][0]) = pre[s][q];
            }
        }
    };
    auto stageB = [&](int cc) {
        const char* wsrc = wb + (size_t)cc * BLKB;
        char* sbb = (char*)sBraw[(NBUF == 2) ? (cc & 1) : 0];
        for (int r = wave; r < RNDS; r += NW)
            gl_lds16(wsrc + r * 1024 + lane * 16, sbb + r * 1024);
    };

    f32x4 acc[OF][4];
#pragma unroll
    for (int o = 0; o < OF; ++o)
#pragma unroll
        for (int p = 0; p < 4; ++p)
#pragma unroll
            for (int r = 0; r < 4; ++r) acc[o][p][r] = 0.f;

    // zero the x-pad column units (col index 0 and 65) once
    if (t < HALO * 8) {
        int row = t >> 3, q = (t >> 1) & 3, cp = (t & 1) ? 65 : 0;
        *reinterpret_cast<bf16x8*>(&sA[row][q][cp][0]) =
            bf16x8{0, 0, 0, 0, 0, 0, 0, 0};
    }

    // prologue: stage phase 0
    stageB(0);
    stageA_load(0);
    stageA_write();

    for (int cc = 0; cc < NCC; ++cc) {
        __syncthreads();               // sB(cc) drained, sA(cc) visible
        if (cc + 1 < NCC) {
            if (PIPE) stageB(cc + 1);  // dbuf: DMA into alternate buffer now
            stageA_load(cc + 1);       // global -> regs, no LDS touch
        }
        const bf16x8* sBv = reinterpret_cast<const bf16x8*>(
            sBraw[(NBUF == 2) ? (cc & 1) : 0]);

#pragma unroll
        for (int dy = 0; dy < 3; ++dy) {
#pragma unroll
            for (int dx = 0; dx < 3; ++dx) {
                bf16x8 pF[4];
#pragma unroll
                for (int p = 0; p < 4; ++p)
                    pF[p] = *reinterpret_cast<const bf16x8*>(
                        &sA[row_l + dy][quad][p * 16 + l15 + dx][0]);
                bf16x8 wF[OF];
#pragma unroll
                for (int o = 0; o < OF; ++o)
                    wF[o] = sBv[((dy * 3 + dx) * 4 + quad) * BN + ocw + o * 16 + l15];
#pragma unroll
                for (int o = 0; o < OF; ++o)
#pragma unroll
                    for (int p = 0; p < 4; ++p)
                        acc[o][p] = __builtin_amdgcn_mfma_f32_16x16x32_bf16(
                            wF[o], pF[p], acc[o][p], 0, 0, 0);
            }
        }
        __syncthreads();               // all reads of sA(cc)/sB(cc) done
        if (cc + 1 < NCC) {
            if (!PIPE) stageB(cc + 1); // single-buf: DMA into the freed buffer
            stageA_write();
        }
    }

    // ---- epilogue. C/D: m(oc) = quad*4+reg, n(pixel) = l15.
    const int prow = r0 + row_l;
#pragma unroll
    for (int o = 0; o < OF; ++o)
#pragma unroll
        for (int reg = 0; reg < 4; ++reg) {
            const int ocl = ocw + o * 16 + quad * 4 + reg;
            const int ocg = nt * BN + ocl;
            if (ocg < CREAL) {
                const float bv = bias[g * CREAL + ocg];
                if (PIXMAJ_OUT) {
                    short* outp = (short*)outv;
                    const size_t pixbase = ((size_t)g * 4096 + prow * 64);
#pragma unroll
                    for (int p = 0; p < 4; ++p) {
                        float v = acc[o][p][reg] + bv;
                        if (LEAKY) v = v >= 0.f ? v : 0.1f * v;
                        outp[(pixbase + p * 16 + l15) * (NT * BN) + ocg] = f2bs(v);
                    }
                } else if (OUT_F32) {
                    float* outp = (float*)outv;
                    const size_t base = ((size_t)(g * CREAL + ocg)) * HW + prow * IMG_W;
#pragma unroll
                    for (int p = 0; p < 4; ++p) {
                        float v = acc[o][p][reg] + bv;
                        if (LEAKY) v = v >= 0.f ? v : 0.1f * v;
                        outp[base + p * 16 + l15] = v;
                    }
                } else {
                    short* outp = (short*)outv;
                    const size_t base = ((size_t)(g * CREAL + ocg)) * HW + prow * IMG_W;
#pragma unroll
                    for (int p = 0; p < 4; ++p) {
                        float v = acc[o][p][reg] + bv;
                        if (LEAKY) v = v >= 0.f ? v : 0.1f * v;
                        outp[base + p * 16 + l15] = f2bs(v);
                    }
                }
            }
        }
}

// ---------------------------------------------------------------------------
// conv1_direct: round-2 verified kernel. Kept as FALLBACK when ws_size is
// too small for the k-split path. 512 blocks, 2/CU, 8 waves/CU.
// ---------------------------------------------------------------------------
__global__ __launch_bounds__(256, 2)
void conv1_direct(const short* __restrict__ inp, const char* __restrict__ wp,
                  const float* __restrict__ bias, short* __restrict__ outp)
{
    __shared__ __align__(16) short sA[2][4][66][4][8];   // 33792 B

    const int b  = blockIdx.x;
    const int g  = b & 7;                     // XCD swizzle: group per XCD
    const int r_ = b >> 3;
    const int pt = r_ & 31;
    const int nt = r_ >> 5;
    const int r0 = pt * 2;

    const int t    = threadIdx.x;
    const int wave = t >> 6, lane = t & 63;
    const int l15  = lane & 15, quad = lane >> 4;

    const int row_l = wave & 1;
    const int ocw   = (wave >> 1) * 32;

    const short* wb    = (const short*)wp + (size_t)(g * 2 + nt) * 16 * 18432;
    const short* wlane = wb + ((size_t)(ocw + l15) * 4 + quad) * 8;

    auto stageDMA = [&](int cc, int buf) {
        int gy = r0 - 1 + wave;               // wave w stages halo row j=w
        if (gy >= 0 && gy < 64) {
            const short* src = inp + ((size_t)cc * 4096 + (size_t)gy * 64) * 32
                                   + (size_t)lane * 8;
#pragma unroll
            for (int c4 = 0; c4 < 4; ++c4)
                gl_lds16(src + c4 * 512, &sA[buf][wave][1 + c4 * 16][0][0]);
        }
    };

    bf16x8 wA[9][2], wB[9][2];
    auto loadW_into = [&](int cc, bf16x8 (&w)[9][2]) {
        const short* ws = wlane + (size_t)cc * 18432;
#pragma unroll
        for (int tap = 0; tap < 9; ++tap)
#pragma unroll
            for (int o = 0; o < 2; ++o)
                w[tap][o] = *reinterpret_cast<const bf16x8*>(
                    ws + tap * 2048 + o * 512);
    };

    f32x4 acc[2][4];
#pragma unroll
    for (int o = 0; o < 2; ++o)
#pragma unroll
        for (int p = 0; p < 4; ++p)
#pragma unroll
            for (int r = 0; r < 4; ++r) acc[o][p][r] = 0.f;

    loadW_into(0, wA);
    stageDMA(0, 0);
    if (t < 64) {
        int buf = t >> 5, row = (t >> 3) & 3, q = (t >> 1) & 3;
        int col = (t & 1) ? 65 : 0;
        *reinterpret_cast<bf16x8*>(&sA[buf][row][col][q][0]) =
            bf16x8{0, 0, 0, 0, 0, 0, 0, 0};
    }
    if (r0 == 0 || r0 == 62) {
        int zr = (r0 == 0) ? 0 : 3;
        for (int i = t; i < 2 * 66 * 4; i += 256) {
            int buf = i / 264, rem = i % 264;
            *reinterpret_cast<bf16x8*>(&sA[buf][zr][rem >> 2][rem & 3][0]) =
                bf16x8{0, 0, 0, 0, 0, 0, 0, 0};
        }
    }

    auto body = [&](int cc, int cur, bf16x8 (&wuse)[9][2], bf16x8 (&wld)[9][2]) {
        __syncthreads();
        if (cc + 1 < 16) {
            stageDMA(cc + 1, cur ^ 1);
            loadW_into(cc + 1, wld);
        }
#pragma unroll
        for (int dy = 0; dy < 3; ++dy)
#pragma unroll
            for (int dx = 0; dx < 3; ++dx) {
                bf16x8 pF[4];
#pragma unroll
                for (int p = 0; p < 4; ++p)
                    pF[p] = *reinterpret_cast<const bf16x8*>(
                        &sA[cur][row_l + dy][p * 16 + l15 + dx][quad][0]);
#pragma unroll
                for (int o = 0; o < 2; ++o)
#pragma unroll
                    for (int p = 0; p < 4; ++p)
                        acc[o][p] = __builtin_amdgcn_mfma_f32_16x16x32_bf16(
                            wuse[dy * 3 + dx][o], pF[p], acc[o][p], 0, 0, 0);
            }
    };

    for (int c2 = 0; c2 < 16; c2 += 2) {
        body(c2,     0, wA, wB);
        body(c2 + 1, 1, wB, wA);
    }

    const int prow = r0 + row_l;
    const size_t pixbase = (size_t)g * 4096 + (size_t)prow * 64;
#pragma unroll
    for (int o = 0; o < 2; ++o)
#pragma unroll
        for (int reg = 0; reg < 4; ++reg) {
            const int ocg = nt * 64 + ocw + o * 16 + quad * 4 + reg;
            const float bv = bias[g * 128 + ocg];
#pragma unroll
            for (int p = 0; p < 4; ++p) {
                float v = acc[o][p][reg] + bv;
                v = v >= 0.f ? v : 0.1f * v;
                outp[(pixbase + p * 16 + l15) * 128 + ocg] = f2bs(v);
            }
        }
}

// ---------------------------------------------------------------------------
// conv1_of4: bytes/FLOP restructure. Evidence: dur == LDS + VMEM + MFMA pipe
// SUM (zero overlap) and occupancy is a weak lever (+8% for 2x). So shrink
// the pipes: each wave owns 64 oc (OF=4) instead of 32 -> the same 36 pF
// LDS reads feed 144 MFMAs (2x) => per-CU LDS-read time halves (25->11.5us).
// Block = 4 waves (row 2 x nt 2) covering 2 px-rows x ALL 128 oc; grid kept
// at 512 via k-split ks=2 (cc 0-7 / 8-15) with fp32 partials + finalize.
// Weights: per-cc burst of all 36 fragments into w[9][4] (144 VGPRs, all
// static indices), issued right after the barrier -> one pipelined VMEM
// stream overlapping the LDS/MFMA tap loop (compiler emits counted vmcnt).
// __launch_bounds__(256,2): 2 blocks/CU is grid-capped anyway; give the
// allocator the full 256-VGPR budget so the burst stays resident.
// ---------------------------------------------------------------------------
__global__ __launch_bounds__(256, 2)
void conv1_of4(const short* __restrict__ inp, const char* __restrict__ wp,
               float* __restrict__ part0, float* __restrict__ part1)
{
    __shared__ __align__(16) short sA[2][4][66][4][8];   // 33792 B

    const int b  = blockIdx.x;
    const int g  = b & 7;                     // XCD swizzle: group per XCD
    const int r_ = b >> 3;
    const int pt = r_ & 31;
    const int ks = (r_ >> 5) & 1;             // K-split half
    const int r0 = pt * 2;
    const int cc0 = ks * 8;

    const int t    = threadIdx.x;
    const int wave = t >> 6, lane = t & 63;
    const int l15  = lane & 15, quad = lane >> 4;

    const int row_l = wave & 1;               // px row within tile
    const int ntw   = wave >> 1;              // oc 64-half

    // W1p layout [g][nt][cc 16][tap 9][oc 64][q 4][ic 8]
    const short* wb    = (const short*)wp + (size_t)(g * 2 + ntw) * 16 * 18432;
    const short* wlane = wb + ((size_t)l15 * 4 + quad) * 8;

    auto stageDMA = [&](int cc, int buf) {
        int gy = r0 - 1 + wave;               // wave w stages halo row j=w
        if (gy >= 0 && gy < 64) {
            const short* src = inp + ((size_t)cc * 4096 + (size_t)gy * 64) * 32
                                   + (size_t)lane * 8;
#pragma unroll
            for (int c4 = 0; c4 < 4; ++c4)
                gl_lds16(src + c4 * 512, &sA[buf][wave][1 + c4 * 16][0][0]);
        }
    };

    f32x4 acc[4][4];
#pragma unroll
    for (int o = 0; o < 4; ++o)
#pragma unroll
        for (int p = 0; p < 4; ++p)
#pragma unroll
            for (int r = 0; r < 4; ++r) acc[o][p][r] = 0.f;

    // prologue: DMA(cc0) into buf0, zero pads / OOB rows (both buffers)
    stageDMA(cc0, 0);
    if (t < 64) {
        int buf = t >> 5, row = (t >> 3) & 3, q = (t >> 1) & 3;
        int col = (t & 1) ? 65 : 0;
        *reinterpret_cast<bf16x8*>(&sA[buf][row][col][q][0]) =
            bf16x8{0, 0, 0, 0, 0, 0, 0, 0};
    }
    if (r0 == 0 || r0 == 62) {
        int zr = (r0 == 0) ? 0 : 3;           // gy=-1 or gy=64 row: zero forever
        for (int i = t; i < 2 * 66 * 4; i += 256) {
            int buf = i / 264, rem = i % 264;
            *reinterpret_cast<bf16x8*>(&sA[buf][zr][rem >> 2][rem & 3][0]) =
                bf16x8{0, 0, 0, 0, 0, 0, 0, 0};
        }
    }

    auto body = [&](int i, int cur) {
        const int cc = cc0 + i;
        __syncthreads();      // publishes sA[cur] (vmcnt(0) drains its DMA)
        if (i + 1 < 8) stageDMA(cc + 1, cur ^ 1);   // in flight during taps
        const short* wcc = wlane + (size_t)cc * 18432;

        // burst-load all 36 weight fragments of this cc (static indices)
        bf16x8 w[9][4];
#pragma unroll
        for (int tap = 0; tap < 9; ++tap)
#pragma unroll
            for (int o = 0; o < 4; ++o)
                w[tap][o] = *reinterpret_cast<const bf16x8*>(
                    wcc + tap * 2048 + o * 512);

#pragma unroll
        for (int dy = 0; dy < 3; ++dy)
#pragma unroll
            for (int dx = 0; dx < 3; ++dx) {
                bf16x8 pF[4];
#pragma unroll
                for (int p = 0; p < 4; ++p)
                    pF[p] = *reinterpret_cast<const bf16x8*>(
                        &sA[cur][row_l + dy][p * 16 + l15 + dx][quad][0]);
#pragma unroll
                for (int o = 0; o < 4; ++o)
#pragma unroll
                    for (int p = 0; p < 4; ++p)
                        acc[o][p] = __builtin_amdgcn_mfma_f32_16x16x32_bf16(
                            w[dy * 3 + dx][o], pF[p], acc[o][p], 0, 0, 0);
            }
    };

    for (int i2 = 0; i2 < 8; i2 += 2) {
        body(i2,     0);
        body(i2 + 1, 1);
    }

    // epilogue: fp32 partial stores. C/D: m(oc)=quad*4+reg, n(pixel)=l15.
    float* pp = ks ? part1 : part0;
    const int prow = r0 + row_l;
    const size_t pixbase = (size_t)g * 4096 + (size_t)prow * 64;
#pragma unroll
    for (int o = 0; o < 4; ++o)
#pragma unroll
        for (int reg = 0; reg < 4; ++reg) {
            const int ocg = ntw * 64 + o * 16 + quad * 4 + reg;
#pragma unroll
            for (int p = 0; p < 4; ++p)
                pp[(pixbase + p * 16 + l15) * 128 + ocg] = acc[o][p][reg];
        }
}

// part0+part1+bias, leaky, pack bf16 -> hid1 [g*4096 pix][128]
__global__ __launch_bounds__(256)
void finalize_conv1(const float* __restrict__ p0, const float* __restrict__ p1,
                    const float* __restrict__ bias, short* __restrict__ outp)
{
    const size_t i8 = ((size_t)blockIdx.x * 256 + threadIdx.x) * 8;
    const int oc0 = (int)(i8 & 127);
    const int g   = (int)(i8 >> 19);          // 4096*128 = 2^19 per group
    float4 a0 = *reinterpret_cast<const float4*>(p0 + i8);
    float4 a1 = *reinterpret_cast<const float4*>(p0 + i8 + 4);
    float4 b0 = *reinterpret_cast<const float4*>(p1 + i8);
    float4 b1 = *reinterpret_cast<const float4*>(p1 + i8 + 4);
    float4 c0 = *reinterpret_cast<const float4*>(bias + g * 128 + oc0);
    float4 c1 = *reinterpret_cast<const float4*>(bias + g * 128 + oc0 + 4);
    float v[8] = {a0.x + b0.x + c0.x, a0.y + b0.y + c0.y,
                  a0.z + b0.z + c0.z, a0.w + b0.w + c0.w,
                  a1.x + b1.x + c1.x, a1.y + b1.y + c1.y,
                  a1.z + b1.z + c1.z, a1.w + b1.w + c1.w};
    ushort8v r;
#pragma unroll
    for (int j = 0; j < 8; ++j) {
        float x = v[j] >= 0.f ? v[j] : 0.1f * v[j];
        r[j] = (unsigned short)f2bs(x);
    }
    *reinterpret_cast<ushort8v*>(outp + i8) = r;
}

// ---------------------------------------------------------------------------
// Fused softmax-over-groups + bilinear params + warp + combine (fp32 out).
// gar channels come from inp_t chunks (layout [cc][4096][32], first 8 chunks).
// ---------------------------------------------------------------------------
__global__ __launch_bounds__(256)
void warp_combine_kernel(const float* __restrict__ oa,
                         const short* __restrict__ inp_t,
                         const float* __restrict__ mask,
                         float* __restrict__ out)
{
    __shared__ __align__(16) float4 sWts[8][6][8];
    __shared__ __align__(16) int4   sIdx[8][6][8];

    const int t = threadIdx.x;

    if (t < 48) {
        int lp = t / 6;
        int k  = t % 6;
        int p  = blockIdx.x * 8 + lp;
        int x  = p & 63, y = p >> 6;

        float l[8];
        float m = -1e30f;
#pragma unroll
        for (int g = 0; g < 8; ++g) {
            l[g] = oa[(size_t)(g * 18 + 12 + k) * HW + p];
            m = fmaxf(m, l[g]);
        }
        float s = 0.f;
#pragma unroll
        for (int g = 0; g < 8; ++g) { l[g] = __expf(l[g] - m); s += l[g]; }
        float inv = 1.f / s;

#pragma unroll
        for (int g = 0; g < 8; ++g) {
            float a  = l[g] * inv;
            float ox = oa[(size_t)(g * 18 + 2 * k)     * HW + p];
            float oy = oa[(size_t)(g * 18 + 2 * k + 1) * HW + p];
            float sx = fminf(fmaxf(((float)x + ox) * (64.f / 63.f) - 0.5f, 0.f), 63.f);
            float sy = fminf(fmaxf(((float)y + oy) * (64.f / 63.f) - 0.5f, 0.f), 63.f);
            float fx0 = floorf(sx), fy0 = floorf(sy);
            int   x0 = (int)fx0,    y0i = (int)fy0;
            float wx = sx - fx0,    wy = sy - fy0;
            int   x1 = min(x0 + 1, 63), y1 = min(y0i + 1, 63);
            sWts[lp][k][g] = make_float4(a * (1.f - wy) * (1.f - wx),
                                         a * (1.f - wy) * wx,
                                         a * wy * (1.f - wx),
                                         a * wy * wx);
            sIdx[lp][k][g] = make_int4(y0i * 64 + x0, y0i * 64 + x1,
                                       y1  * 64 + x0, y1  * 64 + x1);
        }
    }
    __syncthreads();

    const int lp = t >> 5;
    const int p  = blockIdx.x * 8 + lp;
    const int c0 = (t & 31) * 8;
    const short* ipc = inp_t + (size_t)(c0 >> 5) * (4096 * 32) + (c0 & 31);

    float acc[8];
#pragma unroll
    for (int j = 0; j < 8; ++j) acc[j] = 0.f;

    for (int g = 0; g < 8; ++g) {
        float4 m0 = *reinterpret_cast<const float4*>(mask + g * 256 + c0);
        float4 m1 = *reinterpret_cast<const float4*>(mask + g * 256 + c0 + 4);
        float mk[8] = {m0.x, m0.y, m0.z, m0.w, m1.x, m1.y, m1.z, m1.w};
#pragma unroll
        for (int k = 0; k < 6; ++k) {
            float4 w  = sWts[lp][k][g];
            int4   id = sIdx[lp][k][g];
            ushort8v v00 = *reinterpret_cast<const ushort8v*>(ipc + (size_t)id.x * 32);
            ushort8v v01 = *reinterpret_cast<const ushort8v*>(ipc + (size_t)id.y * 32);
            ushort8v v10 = *reinterpret_cast<const ushort8v*>(ipc + (size_t)id.z * 32);
            ushort8v v11 = *reinterpret_cast<const ushort8v*>(ipc + (size_t)id.w * 32);
#pragma unroll
            for (int j = 0; j < 8; ++j) {
                float sv = w.x * bfbits2f(v00[j]) + w.y * bfbits2f(v01[j])
                         + w.z * bfbits2f(v10[j]) + w.w * bfbits2f(v11[j]);
                acc[j] = fmaf(mk[j], sv, acc[j]);
            }
        }
    }
#pragma unroll
    for (int j = 0; j < 8; ++j)
        out[(size_t)(c0 + j) * HW + p] = acc[j];
}

// ---------------------------------------------------------------------------
// Workspace: old layout (peak ~25 MB) + k-split partials at 28 MB / 44 MB
// (only used when ws_size >= 60 MB; guarded at launch).
// ---------------------------------------------------------------------------
extern "C" void kernel_launch(void* const* d_in, const int* in_sizes, int n_in,
                              void* d_out, int out_size, void* d_ws, size_t ws_size,
                              hipStream_t stream)
{
    (void)in_sizes; (void)n_in; (void)out_size;
    const float* gar  = (const float*)d_in[0];
    const float* cond = (const float*)d_in[1];
    const float* mask = (const float*)d_in[2];
    const float* W1   = (const float*)d_in[3];
    const float* b1   = (const float*)d_in[4];
    const float* W2   = (const float*)d_in[5];
    const float* b2   = (const float*)d_in[6];
    const float* W3   = (const float*)d_in[7];
    const float* b3   = (const float*)d_in[8];
    const float* W4   = (const float*)d_in[9];
    const float* b4   = (const float*)d_in[10];
    float* out = (float*)d_out;

    char* ws = (char*)d_ws;
    short* inp_t  = (short*)(ws);
    char*  W1p    = ws + (4u << 20);
    short* hid2_t = (short*)(ws + (4u << 20));          // overlays dead W1p
    short* hid3_t = (short*)(ws + (8u << 20));          // overlays dead W1p
    float* oa     = (float*)(ws + (10u << 20) + (512u << 10));
    char*  W2p    = ws + (14u << 20);
    char*  W3p    = ws + (15u << 20) + (512u << 10);
    char*  W4p    = ws + (16u << 20);
    short* hid1_t = (short*)(ws + (17u << 20));
    float* part0  = (float*)(ws + (28u << 20));         // 16 MB (k-split only)
    float* part1  = (float*)(ws + (44u << 20));         // 16 MB (k-split only)

    // 312 weight-pack blocks + 2048 input-transpose blocks, one launch
    pack_all<<<2360, 256, 0, stream>>>(gar, cond, W1, W2, W3, W4,
                                       inp_t, W1p, W2p, W3p, W4p);

    if (ws_size >= ((size_t)60 << 20)) {
        // conv1 OF=4 k-split: 512 blocks, wave = 64px x 64oc, w-burst regs
        conv1_of4<<<512, 256, 0, stream>>>(inp_t, W1p, part0, part1);
        finalize_conv1<<<2048, 256, 0, stream>>>(part0, part1, b1, hid1_t);
    } else {
        conv1_direct<<<512, 256, 0, stream>>>(inp_t, W1p, b1, hid1_t);
    }
    // conv2: 128->64, ROWS=2, BN=64, OF=1, NT=1, NW=8, PIPE=1 (unchanged)
    conv_mfma<128, 64, 64, 2, 1, 1, 8, 1, true, true, false>
        <<<256, 512, 0, stream>>>(hid1_t, W2p, b2, hid2_t);
    // conv3: 64->32, ROWS=2, BN=32, OF=1, NT=1, NW=4, PIPE=1 (unchanged)
    conv_mfma<64, 32, 32, 2, 1, 1, 4, 1, true, true, false>
        <<<256, 256, 0, stream>>>(hid2_t, W3p, b3, hid3_t);
    // conv4: 32->18 (pad 32), ROWS=2, BN=32, OF=1, NT=1, NW=4 (unchanged)
    conv_mfma<32, 18, 32, 2, 1, 1, 4, 1, false, false, true>
        <<<256, 256, 0, stream>>>(hid3_t, W4p, b4, oa);

    warp_combine_kernel<<<512, 256, 0, stream>>>(oa, inp_t, mask, out);
}

// Round 5
// 203.816 us; speedup vs baseline: 1.0310x; 1.0310x over previous
//
#include <hip/hip_runtime.h>
#include <hip/hip_bf16.h>

typedef __hip_bfloat16 bf16;
typedef unsigned short ushort8v __attribute__((ext_vector_type(8)));
typedef short  s16x4  __attribute__((ext_vector_type(4)));
typedef short  bf16x8 __attribute__((ext_vector_type(8)));   // 8 bf16 (4 VGPRs)
typedef float  f32x4  __attribute__((ext_vector_type(4)));

#define HW 4096
#define IMG_W 64

__device__ __forceinline__ float bfbits2f(unsigned short u) {
    return __uint_as_float(((unsigned int)u) << 16);
}
__device__ __forceinline__ short f2bs(float f) {
    bf16 h = __float2bfloat16(f);
    return *reinterpret_cast<short*>(&h);
}

// async global->LDS, 16B per lane (wave-uniform LDS base + lane*16 scatter).
__device__ __forceinline__ void gl_lds16(const void* g, void* s) {
    __builtin_amdgcn_global_load_lds(
        (const __attribute__((address_space(1))) unsigned int*)g,
        (__attribute__((address_space(3))) unsigned int*)s, 16, 0, 0);
}

// ---------------------------------------------------------------------------
// pack_input: concat(gar,cond) fp32 [512][4096] -> inp_t bf16 in chunked
// layout [cc=16][pix=4096][32ch]  (64 B per pixel per cc-chunk).
// ---------------------------------------------------------------------------
__device__ void pack_input_dev(const float* __restrict__ gar,
                               const float* __restrict__ cond,
                               short* __restrict__ outp, int bx2, float* tile)
{
    int bx = bx2 & 127;                // px tile (128)
    int by = bx2 >> 7;                 // ch tile (16) == cc chunk
    int tx = threadIdx.x & 31;
    int ty = threadIdx.x >> 5;
#pragma unroll
    for (int i = 0; i < 4; ++i) {
        int c = by * 32 + ty + i * 8;
        const float* src = (c < 256) ? (gar + (size_t)c * HW)
                                     : (cond + (size_t)(c - 256) * HW);
        tile[(ty + i * 8) * 33 + tx] = src[bx * 32 + tx];
    }
    __syncthreads();
#pragma unroll
    for (int i = 0; i < 4; ++i) {
        int p = bx * 32 + ty + i * 8;
        outp[((size_t)by * 4096 + p) * 32 + tx] = f2bs(tile[tx * 33 + ty + i * 8]);
    }
}

// ---------------------------------------------------------------------------
// pack_w: W fp32 [G][CREAL][CIN][3][3] -> bf16 blocks.
// COAL=false (conv2-4): [g][nt][cc][tap 9][q 4][oc BN][8 ic]   (old layout)
// COAL=true  (conv1)  : [g][nt][cc][tap 9][oc BN][q 4][8 ic]   -> a wave's
//   64-lane weight-fragment load is one contiguous 1 KB span.
// BLKB = 9*4*BN*16 bytes either way.
// ---------------------------------------------------------------------------
template<int CIN, int CREAL, int BN, int NT, bool COAL>
__device__ void pack_w_dev(const float* __restrict__ wgt, char* __restrict__ wp,
                           int bx, short* sT)
{
    constexpr int NCC  = CIN / 32;
    constexpr int BLKB = 9 * 4 * BN * 16;

    const int t  = threadIdx.x;
    const int cc = bx % NCC;
    const int nt = (bx / NCC) % NT;
    const int g  = bx / (NT * NCC);

    for (int i = t; i < BLKB / 8; i += 256)
        reinterpret_cast<s16x4*>(sT)[i] = s16x4{0, 0, 0, 0};
    __syncthreads();

    int ocmax = CREAL - nt * BN; if (ocmax > BN) ocmax = BN;
    const size_t base = ((size_t)(g * CREAL + nt * BN) * CIN + cc * 32) * 9;
    for (int i = t; i < ocmax * 288; i += 256) {
        int oc = i / 288;
        int r  = i % 288;                      // ic*9 + tap
        int ic = r / 9, tap = r % 9;
        size_t idx;
        if (COAL) idx = (size_t)(((tap * BN + oc) * 4 + (ic >> 3)) * 8 + (ic & 7));
        else      idx = (size_t)(((tap * 4 + (ic >> 3)) * BN + oc) * 8 + (ic & 7));
        sT[idx] = f2bs(wgt[base + (size_t)oc * CIN * 9 + r]);
    }
    __syncthreads();

    const s16x4* src = reinterpret_cast<const s16x4*>(sT);
    s16x4* dst = reinterpret_cast<s16x4*>(wp + (size_t)bx * BLKB);
    for (int i = t; i < BLKB / 8; i += 256)
        dst[i] = src[i];
}

// All packing in one launch (block-range dispatch; branch is block-uniform).
__global__ __launch_bounds__(256)
void pack_all(const float* __restrict__ gar, const float* __restrict__ cond,
              const float* __restrict__ W1, const float* __restrict__ W2,
              const float* __restrict__ W3, const float* __restrict__ W4,
              short* inp_t, char* W1p, char* W2p, char* W3p, char* W4p)
{
    __shared__ __align__(16) short sbuf[9 * 4 * 64 * 8];   // 36864 B
    int bx = blockIdx.x;
    if (bx < 256)      pack_w_dev<512, 128, 64, 2, true >(W1, W1p, bx,       sbuf);
    else if (bx < 288) pack_w_dev<128,  64, 64, 1, false>(W2, W2p, bx - 256, sbuf);
    else if (bx < 304) pack_w_dev< 64,  32, 32, 1, false>(W3, W3p, bx - 288, sbuf);
    else if (bx < 312) pack_w_dev< 32,  18, 32, 1, false>(W4, W4p, bx - 304, sbuf);
    else pack_input_dev(gar, cond, inp_t, bx - 312, (float*)sbuf);
}

// ---------------------------------------------------------------------------
// Implicit-GEMM 3x3 SAME conv, bf16 MFMA 16x16x32, conflict-free LDS.
// (old template — still used for conv2/3/4; input layout [pix][ICP])
// ---------------------------------------------------------------------------
template<int ICP, int CREAL, int BN, int ROWS, int OF, int NT, int NW, int PIPE,
         bool PIXMAJ_OUT, bool LEAKY, bool OUT_F32>
__global__ __launch_bounds__(NW * 64, 2)
void conv_mfma(const short* __restrict__ inp, const char* __restrict__ wp,
               const float* __restrict__ bias, void* __restrict__ outv)
{
    constexpr int NCC  = ICP / 32;
    constexpr int HALO = ROWS + 2;
    constexpr int NPT  = 4096 / (ROWS * 64);
    constexpr int BLKB = 9 * 4 * BN * 16;
    constexpr int RNDS = BLKB / 1024;
    constexpr int NBUF = (PIPE && NCC > 1) ? 2 : 1;
    constexpr int SMAX = (HALO + NW - 1) / NW;

    __shared__ __align__(16) short sA[HALO][4][68][8];
    __shared__ __align__(16) char  sBraw[NBUF][BLKB];

    const int b  = blockIdx.x;
    const int g  = b & 7;                     // XCD swizzle: group per XCD
    const int r_ = b >> 3;
    const int pt = r_ % NPT;
    const int nt = r_ / NPT;
    const int r0 = pt * ROWS;

    const int t    = threadIdx.x;
    const int wave = t >> 6, lane = t & 63;
    const int l15  = lane & 15, quad = lane >> 4;

    int row_l, ocw;
    if (NW == 8) {
        if (ROWS == 4) { row_l = wave >> 1; ocw = (wave & 1) * (BN / 2); }
        else           { row_l = wave >> 2; ocw = (wave & 3) * (BN / 4); }
    } else {
        row_l = (ROWS == 4) ? wave : (wave & 1);
        ocw   = (ROWS == 4) ? 0 : (wave >> 1) * (BN / 2);
    }

    const size_t gpix = (ICP == 512) ? 0 : ((size_t)g * 4096);
    const char*  wb   = wp + (size_t)((g * NT + nt) * NCC) * BLKB;

    // sA staging: thread -> (col, row-slice); rows j = r2, r2+NW, ...
    const int acol = t & 63;
    const int r2   = t >> 6;

    bf16x8 pre[SMAX][4];

    auto stageA_load = [&](int cc) {
#pragma unroll
        for (int s = 0; s < SMAX; ++s) {
            int j = r2 + s * NW;
            if (j < HALO) {
                int gy = r0 - 1 + j;
                if (gy >= 0 && gy < 64) {
                    const short* sp = inp + ((gpix + gy * 64 + acol) * ICP + cc * 32);
#pragma unroll
                    for (int q = 0; q < 4; ++q)
                        pre[s][q] = *reinterpret_cast<const bf16x8*>(sp + q * 8);
                } else {
#pragma unroll
                    for (int q = 0; q < 4; ++q)
                        pre[s][q] = bf16x8{0, 0, 0, 0, 0, 0, 0, 0};
                }
            }
        }
    };
    auto stageA_write = [&]() {
#pragma unroll
        for (int s = 0; s < SMAX; ++s) {
            int j = r2 + s * NW;
            if (j < HALO) {
#pragma unroll
                for (int q = 0; q < 4; ++q)
                    *reinterpret_cast<bf16x8*>(&sA[j][q][acol + 1][0]) = pre[s][q];
            }
        }
    };
    auto stageB = [&](int cc) {
        const char* wsrc = wb + (size_t)cc * BLKB;
        char* sbb = (char*)sBraw[(NBUF == 2) ? (cc & 1) : 0];
        for (int r = wave; r < RNDS; r += NW)
            gl_lds16(wsrc + r * 1024 + lane * 16, sbb + r * 1024);
    };

    f32x4 acc[OF][4];
#pragma unroll
    for (int o = 0; o < OF; ++o)
#pragma unroll
        for (int p = 0; p < 4; ++p)
#pragma unroll
            for (int r = 0; r < 4; ++r) acc[o][p][r] = 0.f;

    // zero the x-pad column units (col index 0 and 65) once
    if (t < HALO * 8) {
        int row = t >> 3, q = (t >> 1) & 3, cp = (t & 1) ? 65 : 0;
        *reinterpret_cast<bf16x8*>(&sA[row][q][cp][0]) =
            bf16x8{0, 0, 0, 0, 0, 0, 0, 0};
    }

    // prologue: stage phase 0
    stageB(0);
    stageA_load(0);
    stageA_write();

    for (int cc = 0; cc < NCC; ++cc) {
        __syncthreads();               // sB(cc) drained, sA(cc) visible
        if (cc + 1 < NCC) {
            if (PIPE) stageB(cc + 1);  // dbuf: DMA into alternate buffer now
            stageA_load(cc + 1);       // global -> regs, no LDS touch
        }
        const bf16x8* sBv = reinterpret_cast<const bf16x8*>(
            sBraw[(NBUF == 2) ? (cc & 1) : 0]);

#pragma unroll
        for (int dy = 0; dy < 3; ++dy) {
#pragma unroll
            for (int dx = 0; dx < 3; ++dx) {
                bf16x8 pF[4];
#pragma unroll
                for (int p = 0; p < 4; ++p)
                    pF[p] = *reinterpret_cast<const bf16x8*>(
                        &sA[row_l + dy][quad][p * 16 + l15 + dx][0]);
                bf16x8 wF[OF];
#pragma unroll
                for (int o = 0; o < OF; ++o)
                    wF[o] = sBv[((dy * 3 + dx) * 4 + quad) * BN + ocw + o * 16 + l15];
#pragma unroll
                for (int o = 0; o < OF; ++o)
#pragma unroll
                    for (int p = 0; p < 4; ++p)
                        acc[o][p] = __builtin_amdgcn_mfma_f32_16x16x32_bf16(
                            wF[o], pF[p], acc[o][p], 0, 0, 0);
            }
        }
        __syncthreads();               // all reads of sA(cc)/sB(cc) done
        if (cc + 1 < NCC) {
            if (!PIPE) stageB(cc + 1); // single-buf: DMA into the freed buffer
            stageA_write();
        }
    }

    // ---- epilogue. C/D: m(oc) = quad*4+reg, n(pixel) = l15.
    const int prow = r0 + row_l;
#pragma unroll
    for (int o = 0; o < OF; ++o)
#pragma unroll
        for (int reg = 0; reg < 4; ++reg) {
            const int ocl = ocw + o * 16 + quad * 4 + reg;
            const int ocg = nt * BN + ocl;
            if (ocg < CREAL) {
                const float bv = bias[g * CREAL + ocg];
                if (PIXMAJ_OUT) {
                    short* outp = (short*)outv;
                    const size_t pixbase = ((size_t)g * 4096 + prow * 64);
#pragma unroll
                    for (int p = 0; p < 4; ++p) {
                        float v = acc[o][p][reg] + bv;
                        if (LEAKY) v = v >= 0.f ? v : 0.1f * v;
                        outp[(pixbase + p * 16 + l15) * (NT * BN) + ocg] = f2bs(v);
                    }
                } else if (OUT_F32) {
                    float* outp = (float*)outv;
                    const size_t base = ((size_t)(g * CREAL + ocg)) * HW + prow * IMG_W;
#pragma unroll
                    for (int p = 0; p < 4; ++p) {
                        float v = acc[o][p][reg] + bv;
                        if (LEAKY) v = v >= 0.f ? v : 0.1f * v;
                        outp[base + p * 16 + l15] = v;
                    }
                } else {
                    short* outp = (short*)outv;
                    const size_t base = ((size_t)(g * CREAL + ocg)) * HW + prow * IMG_W;
#pragma unroll
                    for (int p = 0; p < 4; ++p) {
                        float v = acc[o][p][reg] + bv;
                        if (LEAKY) v = v >= 0.f ? v : 0.1f * v;
                        outp[base + p * 16 + l15] = f2bs(v);
                    }
                }
            }
        }
}

// ---------------------------------------------------------------------------
// conv1_direct: round-2 verified kernel. Kept as FALLBACK when ws_size is
// too small for the k-split path. 512 blocks, 2/CU, 8 waves/CU.
// ---------------------------------------------------------------------------
__global__ __launch_bounds__(256, 2)
void conv1_direct(const short* __restrict__ inp, const char* __restrict__ wp,
                  const float* __restrict__ bias, short* __restrict__ outp)
{
    __shared__ __align__(16) short sA[2][4][66][4][8];   // 33792 B

    const int b  = blockIdx.x;
    const int g  = b & 7;                     // XCD swizzle: group per XCD
    const int r_ = b >> 3;
    const int pt = r_ & 31;
    const int nt = r_ >> 5;
    const int r0 = pt * 2;

    const int t    = threadIdx.x;
    const int wave = t >> 6, lane = t & 63;
    const int l15  = lane & 15, quad = lane >> 4;

    const int row_l = wave & 1;
    const int ocw   = (wave >> 1) * 32;

    const short* wb    = (const short*)wp + (size_t)(g * 2 + nt) * 16 * 18432;
    const short* wlane = wb + ((size_t)(ocw + l15) * 4 + quad) * 8;

    auto stageDMA = [&](int cc, int buf) {
        int gy = r0 - 1 + wave;               // wave w stages halo row j=w
        if (gy >= 0 && gy < 64) {
            const short* src = inp + ((size_t)cc * 4096 + (size_t)gy * 64) * 32
                                   + (size_t)lane * 8;
#pragma unroll
            for (int c4 = 0; c4 < 4; ++c4)
                gl_lds16(src + c4 * 512, &sA[buf][wave][1 + c4 * 16][0][0]);
        }
    };

    bf16x8 wA[9][2], wB[9][2];
    auto loadW_into = [&](int cc, bf16x8 (&w)[9][2]) {
        const short* ws = wlane + (size_t)cc * 18432;
#pragma unroll
        for (int tap = 0; tap < 9; ++tap)
#pragma unroll
            for (int o = 0; o < 2; ++o)
                w[tap][o] = *reinterpret_cast<const bf16x8*>(
                    ws + tap * 2048 + o * 512);
    };

    f32x4 acc[2][4];
#pragma unroll
    for (int o = 0; o < 2; ++o)
#pragma unroll
        for (int p = 0; p < 4; ++p)
#pragma unroll
            for (int r = 0; r < 4; ++r) acc[o][p][r] = 0.f;

    loadW_into(0, wA);
    stageDMA(0, 0);
    if (t < 64) {
        int buf = t >> 5, row = (t >> 3) & 3, q = (t >> 1) & 3;
        int col = (t & 1) ? 65 : 0;
        *reinterpret_cast<bf16x8*>(&sA[buf][row][col][q][0]) =
            bf16x8{0, 0, 0, 0, 0, 0, 0, 0};
    }
    if (r0 == 0 || r0 == 62) {
        int zr = (r0 == 0) ? 0 : 3;
        for (int i = t; i < 2 * 66 * 4; i += 256) {
            int buf = i / 264, rem = i % 264;
            *reinterpret_cast<bf16x8*>(&sA[buf][zr][rem >> 2][rem & 3][0]) =
                bf16x8{0, 0, 0, 0, 0, 0, 0, 0};
        }
    }

    auto body = [&](int cc, int cur, bf16x8 (&wuse)[9][2], bf16x8 (&wld)[9][2]) {
        __syncthreads();
        if (cc + 1 < 16) {
            stageDMA(cc + 1, cur ^ 1);
            loadW_into(cc + 1, wld);
        }
#pragma unroll
        for (int dy = 0; dy < 3; ++dy)
#pragma unroll
            for (int dx = 0; dx < 3; ++dx) {
                bf16x8 pF[4];
#pragma unroll
                for (int p = 0; p < 4; ++p)
                    pF[p] = *reinterpret_cast<const bf16x8*>(
                        &sA[cur][row_l + dy][p * 16 + l15 + dx][quad][0]);
#pragma unroll
                for (int o = 0; o < 2; ++o)
#pragma unroll
                    for (int p = 0; p < 4; ++p)
                        acc[o][p] = __builtin_amdgcn_mfma_f32_16x16x32_bf16(
                            wuse[dy * 3 + dx][o], pF[p], acc[o][p], 0, 0, 0);
            }
    };

    for (int c2 = 0; c2 < 16; c2 += 2) {
        body(c2,     0, wA, wB);
        body(c2 + 1, 1, wB, wA);
    }

    const int prow = r0 + row_l;
    const size_t pixbase = (size_t)g * 4096 + (size_t)prow * 64;
#pragma unroll
    for (int o = 0; o < 2; ++o)
#pragma unroll
        for (int reg = 0; reg < 4; ++reg) {
            const int ocg = nt * 64 + ocw + o * 16 + quad * 4 + reg;
            const float bv = bias[g * 128 + ocg];
#pragma unroll
            for (int p = 0; p < 4; ++p) {
                float v = acc[o][p][reg] + bv;
                v = v >= 0.f ? v : 0.1f * v;
                outp[(pixbase + p * 16 + l15) * 128 + ocg] = f2bs(v);
            }
        }
}

// ---------------------------------------------------------------------------
// conv1_r4: schedule fix + weight-traffic fix.
// Evidence through round 4: duration == SUM of pipe times (zero overlap);
// compiler always sinks weight loads to their MFMA uses (VGPR=64 despite a
// 144-reg burst in source), so each tap serializes VMEM-wait -> MFMA.
//  FIX A (schedule): tap-level register double-buffer w[2][4] (32 VGPR,
//   static parity indexing). Each tap issues the NEXT tap's 4 loads, then
//   sched_barrier(0) pins them BEFORE this tap's 16 MFMAs -> every load has
//   ~16 MFMA (~310 cyc) of slack; compiler emits counted vmcnt. At tap 8,
//   wcc+(tap+1)*2048 lands exactly on the next cc's tap 0, so the pipeline
//   crosses cc boundaries/barriers with values resident in regs.
//  FIX B (traffic): ROWS=4 tile (256 px x 128 oc, 8 waves, wave = row(0-3)
//   x oc-half). Weight L2 re-reads halve: ~75 -> ~37 MB/XCD (~8.5 us).
// Grid: 16 pt x 2 ks x 8 g = 256 blocks x 512 thr; k-split partials +
// finalize as in round 3. LDS 49.5 KB dbuf, one barrier per cc.
// ---------------------------------------------------------------------------
__global__ __launch_bounds__(512, 2)
void conv1_r4(const short* __restrict__ inp, const char* __restrict__ wp,
              float* __restrict__ part0, float* __restrict__ part1)
{
    __shared__ __align__(16) short sA[2][6][66][4][8];   // 50688 B

    const int b  = blockIdx.x;
    const int g  = b & 7;                     // XCD swizzle: group per XCD
    const int r_ = b >> 3;
    const int pt = r_ & 15;
    const int ks = (r_ >> 4) & 1;             // K-split half
    const int r0 = pt * 4;
    const int cc0 = ks * 8;

    const int t    = threadIdx.x;
    const int wave = t >> 6, lane = t & 63;
    const int l15  = lane & 15, quad = lane >> 4;

    const int row_l = wave & 3;               // px row within tile (0-3)
    const int ntw   = wave >> 2;              // oc 64-half (0-1)

    // W1p layout [g][nt][cc 16][tap 9][oc 64][q 4][ic 8]
    const short* wb    = (const short*)wp + (size_t)(g * 2 + ntw) * 16 * 18432;
    const short* wlane = wb + ((size_t)l15 * 4 + quad) * 8;

    auto stageDMA = [&](int cc, int buf) {
        if (wave < 6) {
            int gy = r0 - 1 + wave;           // wave w stages halo row j=w
            if (gy >= 0 && gy < 64) {
                const short* src = inp + ((size_t)cc * 4096 + (size_t)gy * 64) * 32
                                       + (size_t)lane * 8;
#pragma unroll
                for (int c4 = 0; c4 < 4; ++c4)
                    gl_lds16(src + c4 * 512, &sA[buf][wave][1 + c4 * 16][0][0]);
            }
        }
    };

    f32x4 acc[4][4];
#pragma unroll
    for (int o = 0; o < 4; ++o)
#pragma unroll
        for (int p = 0; p < 4; ++p)
#pragma unroll
            for (int r = 0; r < 4; ++r) acc[o][p][r] = 0.f;

    // prologue: DMA(cc0) into buf0, zero pads / OOB rows (both buffers)
    stageDMA(cc0, 0);
    if (t < 96) {
        int buf = t / 48, rem = t % 48;
        int row = rem >> 3, q = (rem >> 1) & 3;
        int col = (t & 1) ? 65 : 0;
        *reinterpret_cast<bf16x8*>(&sA[buf][row][col][q][0]) =
            bf16x8{0, 0, 0, 0, 0, 0, 0, 0};
    }
    if (r0 == 0 || r0 == 60) {
        int zr = (r0 == 0) ? 0 : 5;           // gy=-1 or gy=64 row: zero forever
        for (int i = t; i < 2 * 66 * 4; i += 512) {
            int buf = i / 264, rem = i % 264;
            *reinterpret_cast<bf16x8*>(&sA[buf][zr][rem >> 2][rem & 3][0]) =
                bf16x8{0, 0, 0, 0, 0, 0, 0, 0};
        }
    }

    // tap-level weight double-buffer (32 VGPR, statically indexed)
    bf16x8 w[2][4];
#pragma unroll
    for (int o = 0; o < 4; ++o)
        w[0][o] = *reinterpret_cast<const bf16x8*>(
            wlane + (size_t)cc0 * 18432 + o * 512);

    auto body = [&](int i, int cur, int par) {
        const int cc = cc0 + i;
        const short* wcc = wlane + (size_t)cc * 18432;
        __syncthreads();      // publishes sA[cur] (vmcnt(0) drains its DMA)
        if (i + 1 < 8) stageDMA(cc + 1, cur ^ 1);   // in flight during taps
#pragma unroll
        for (int tap = 0; tap < 9; ++tap) {
            const int cb = (tap + par) & 1, nb = cb ^ 1;
            const int dy = tap / 3, dx = tap % 3;
            // issue NEXT tap's weight loads (tap 8 -> next cc's tap 0; the
            // address wcc+9*2048 == next cc's tap 0 by layout). Always valid
            // memory (worst case = 16B at W1p end, dead workspace).
            const short* nsrc = wcc + (size_t)(tap + 1) * 2048;
#pragma unroll
            for (int o = 0; o < 4; ++o)
                w[nb][o] = *reinterpret_cast<const bf16x8*>(nsrc + o * 512);
            __builtin_amdgcn_sched_barrier(0);   // pin: loads issue pre-MFMA
            bf16x8 pF[4];
#pragma unroll
            for (int p = 0; p < 4; ++p)
                pF[p] = *reinterpret_cast<const bf16x8*>(
                    &sA[cur][row_l + dy][p * 16 + l15 + dx][quad][0]);
#pragma unroll
            for (int o = 0; o < 4; ++o)
#pragma unroll
                for (int p = 0; p < 4; ++p)
                    acc[o][p] = __builtin_amdgcn_mfma_f32_16x16x32_bf16(
                        w[cb][o], pF[p], acc[o][p], 0, 0, 0);
        }
    };

    // 9 taps flip the w-buffer parity each cc: par = i & 1 (9*i mod 2).
    for (int i2 = 0; i2 < 8; i2 += 2) {
        body(i2,     0, 0);
        body(i2 + 1, 1, 1);
    }

    // epilogue: fp32 partial stores. C/D: m(oc)=quad*4+reg, n(pixel)=l15.
    float* pp = ks ? part1 : part0;
    const int prow = r0 + row_l;
    const size_t pixbase = (size_t)g * 4096 + (size_t)prow * 64;
#pragma unroll
    for (int o = 0; o < 4; ++o)
#pragma unroll
        for (int reg = 0; reg < 4; ++reg) {
            const int ocg = ntw * 64 + o * 16 + quad * 4 + reg;
#pragma unroll
            for (int p = 0; p < 4; ++p)
                pp[(pixbase + p * 16 + l15) * 128 + ocg] = acc[o][p][reg];
        }
}

// part0+part1+bias, leaky, pack bf16 -> hid1 [g*4096 pix][128]
__global__ __launch_bounds__(256)
void finalize_conv1(const float* __restrict__ p0, const float* __restrict__ p1,
                    const float* __restrict__ bias, short* __restrict__ outp)
{
    const size_t i8 = ((size_t)blockIdx.x * 256 + threadIdx.x) * 8;
    const int oc0 = (int)(i8 & 127);
    const int g   = (int)(i8 >> 19);          // 4096*128 = 2^19 per group
    float4 a0 = *reinterpret_cast<const float4*>(p0 + i8);
    float4 a1 = *reinterpret_cast<const float4*>(p0 + i8 + 4);
    float4 b0 = *reinterpret_cast<const float4*>(p1 + i8);
    float4 b1 = *reinterpret_cast<const float4*>(p1 + i8 + 4);
    float4 c0 = *reinterpret_cast<const float4*>(bias + g * 128 + oc0);
    float4 c1 = *reinterpret_cast<const float4*>(bias + g * 128 + oc0 + 4);
    float v[8] = {a0.x + b0.x + c0.x, a0.y + b0.y + c0.y,
                  a0.z + b0.z + c0.z, a0.w + b0.w + c0.w,
                  a1.x + b1.x + c1.x, a1.y + b1.y + c1.y,
                  a1.z + b1.z + c1.z, a1.w + b1.w + c1.w};
    ushort8v r;
#pragma unroll
    for (int j = 0; j < 8; ++j) {
        float x = v[j] >= 0.f ? v[j] : 0.1f * v[j];
        r[j] = (unsigned short)f2bs(x);
    }
    *reinterpret_cast<ushort8v*>(outp + i8) = r;
}

// ---------------------------------------------------------------------------
// Fused softmax-over-groups + bilinear params + warp + combine (fp32 out).
// gar channels come from inp_t chunks (layout [cc][4096][32], first 8 chunks).
// ---------------------------------------------------------------------------
__global__ __launch_bounds__(256)
void warp_combine_kernel(const float* __restrict__ oa,
                         const short* __restrict__ inp_t,
                         const float* __restrict__ mask,
                         float* __restrict__ out)
{
    __shared__ __align__(16) float4 sWts[8][6][8];
    __shared__ __align__(16) int4   sIdx[8][6][8];

    const int t = threadIdx.x;

    if (t < 48) {
        int lp = t / 6;
        int k  = t % 6;
        int p  = blockIdx.x * 8 + lp;
        int x  = p & 63, y = p >> 6;

        float l[8];
        float m = -1e30f;
#pragma unroll
        for (int g = 0; g < 8; ++g) {
            l[g] = oa[(size_t)(g * 18 + 12 + k) * HW + p];
            m = fmaxf(m, l[g]);
        }
        float s = 0.f;
#pragma unroll
        for (int g = 0; g < 8; ++g) { l[g] = __expf(l[g] - m); s += l[g]; }
        float inv = 1.f / s;

#pragma unroll
        for (int g = 0; g < 8; ++g) {
            float a  = l[g] * inv;
            float ox = oa[(size_t)(g * 18 + 2 * k)     * HW + p];
            float oy = oa[(size_t)(g * 18 + 2 * k + 1) * HW + p];
            float sx = fminf(fmaxf(((float)x + ox) * (64.f / 63.f) - 0.5f, 0.f), 63.f);
            float sy = fminf(fmaxf(((float)y + oy) * (64.f / 63.f) - 0.5f, 0.f), 63.f);
            float fx0 = floorf(sx), fy0 = floorf(sy);
            int   x0 = (int)fx0,    y0i = (int)fy0;
            float wx = sx - fx0,    wy = sy - fy0;
            int   x1 = min(x0 + 1, 63), y1 = min(y0i + 1, 63);
            sWts[lp][k][g] = make_float4(a * (1.f - wy) * (1.f - wx),
                                         a * (1.f - wy) * wx,
                                         a * wy * (1.f - wx),
                                         a * wy * wx);
            sIdx[lp][k][g] = make_int4(y0i * 64 + x0, y0i * 64 + x1,
                                       y1  * 64 + x0, y1  * 64 + x1);
        }
    }
    __syncthreads();

    const int lp = t >> 5;
    const int p  = blockIdx.x * 8 + lp;
    const int c0 = (t & 31) * 8;
    const short* ipc = inp_t + (size_t)(c0 >> 5) * (4096 * 32) + (c0 & 31);

    float acc[8];
#pragma unroll
    for (int j = 0; j < 8; ++j) acc[j] = 0.f;

    for (int g = 0; g < 8; ++g) {
        float4 m0 = *reinterpret_cast<const float4*>(mask + g * 256 + c0);
        float4 m1 = *reinterpret_cast<const float4*>(mask + g * 256 + c0 + 4);
        float mk[8] = {m0.x, m0.y, m0.z, m0.w, m1.x, m1.y, m1.z, m1.w};
#pragma unroll
        for (int k = 0; k < 6; ++k) {
            float4 w  = sWts[lp][k][g];
            int4   id = sIdx[lp][k][g];
            ushort8v v00 = *reinterpret_cast<const ushort8v*>(ipc + (size_t)id.x * 32);
            ushort8v v01 = *reinterpret_cast<const ushort8v*>(ipc + (size_t)id.y * 32);
            ushort8v v10 = *reinterpret_cast<const ushort8v*>(ipc + (size_t)id.z * 32);
            ushort8v v11 = *reinterpret_cast<const ushort8v*>(ipc + (size_t)id.w * 32);
#pragma unroll
            for (int j = 0; j < 8; ++j) {
                float sv = w.x * bfbits2f(v00[j]) + w.y * bfbits2f(v01[j])
                         + w.z * bfbits2f(v10[j]) + w.w * bfbits2f(v11[j]);
                acc[j] = fmaf(mk[j], sv, acc[j]);
            }
        }
    }
#pragma unroll
    for (int j = 0; j < 8; ++j)
        out[(size_t)(c0 + j) * HW + p] = acc[j];
}

// ---------------------------------------------------------------------------
// Workspace: old layout (peak ~25 MB) + k-split partials at 28 MB / 44 MB
// (only used when ws_size >= 60 MB; guarded at launch).
// ---------------------------------------------------------------------------
extern "C" void kernel_launch(void* const* d_in, const int* in_sizes, int n_in,
                              void* d_out, int out_size, void* d_ws, size_t ws_size,
                              hipStream_t stream)
{
    (void)in_sizes; (void)n_in; (void)out_size;
    const float* gar  = (const float*)d_in[0];
    const float* cond = (const float*)d_in[1];
    const float* mask = (const float*)d_in[2];
    const float* W1   = (const float*)d_in[3];
    const float* b1   = (const float*)d_in[4];
    const float* W2   = (const float*)d_in[5];
    const float* b2   = (const float*)d_in[6];
    const float* W3   = (const float*)d_in[7];
    const float* b3   = (const float*)d_in[8];
    const float* W4   = (const float*)d_in[9];
    const float* b4   = (const float*)d_in[10];
    float* out = (float*)d_out;

    char* ws = (char*)d_ws;
    short* inp_t  = (short*)(ws);
    char*  W1p    = ws + (4u << 20);
    short* hid2_t = (short*)(ws + (4u << 20));          // overlays dead W1p
    short* hid3_t = (short*)(ws + (8u << 20));          // overlays dead W1p
    float* oa     = (float*)(ws + (10u << 20) + (512u << 10));
    char*  W2p    = ws + (14u << 20);
    char*  W3p    = ws + (15u << 20) + (512u << 10);
    char*  W4p    = ws + (16u << 20);
    short* hid1_t = (short*)(ws + (17u << 20));
    float* part0  = (float*)(ws + (28u << 20));         // 16 MB (k-split only)
    float* part1  = (float*)(ws + (44u << 20));         // 16 MB (k-split only)

    // 312 weight-pack blocks + 2048 input-transpose blocks, one launch
    pack_all<<<2360, 256, 0, stream>>>(gar, cond, W1, W2, W3, W4,
                                       inp_t, W1p, W2p, W3p, W4p);

    if (ws_size >= ((size_t)60 << 20)) {
        // conv1 ROWS=4 + pipelined reg-dbuf weights (see conv1_r4 comment)
        conv1_r4<<<256, 512, 0, stream>>>(inp_t, W1p, part0, part1);
        finalize_conv1<<<2048, 256, 0, stream>>>(part0, part1, b1, hid1_t);
    } else {
        conv1_direct<<<512, 256, 0, stream>>>(inp_t, W1p, b1, hid1_t);
    }
    // conv2: 128->64, ROWS=2, BN=64, OF=1, NT=1, NW=8, PIPE=1 (unchanged)
    conv_mfma<128, 64, 64, 2, 1, 1, 8, 1, true, true, false>
        <<<256, 512, 0, stream>>>(hid1_t, W2p, b2, hid2_t);
    // conv3: 64->32, ROWS=2, BN=32, OF=1, NT=1, NW=4, PIPE=1 (unchanged)
    conv_mfma<64, 32, 32, 2, 1, 1, 4, 1, true, true, false>
        <<<256, 256, 0, stream>>>(hid2_t, W3p, b3, hid3_t);
    // conv4: 32->18 (pad 32), ROWS=2, BN=32, OF=1, NT=1, NW=4 (unchanged)
    conv_mfma<32, 18, 32, 2, 1, 1, 4, 1, false, false, true>
        <<<256, 256, 0, stream>>>(hid3_t, W4p, b4, oa);

    warp_combine_kernel<<<512, 256, 0, stream>>>(oa, inp_t, mask, out);
}

// Round 6
// 199.812 us; speedup vs baseline: 1.0517x; 1.0200x over previous
//
#include <hip/hip_runtime.h>
#include <hip/hip_bf16.h>

typedef __hip_bfloat16 bf16;
typedef unsigned short ushort8v __attribute__((ext_vector_type(8)));
typedef short  s16x4  __attribute__((ext_vector_type(4)));
typedef short  bf16x8 __attribute__((ext_vector_type(8)));   // 8 bf16 (4 VGPRs)
typedef float  f32x4  __attribute__((ext_vector_type(4)));

#define HW 4096
#define IMG_W 64

__device__ __forceinline__ float bfbits2f(unsigned short u) {
    return __uint_as_float(((unsigned int)u) << 16);
}
__device__ __forceinline__ short f2bs(float f) {
    bf16 h = __float2bfloat16(f);
    return *reinterpret_cast<short*>(&h);
}

// async global->LDS, 16B per lane (wave-uniform LDS base + lane*16 scatter).
__device__ __forceinline__ void gl_lds16(const void* g, void* s) {
    __builtin_amdgcn_global_load_lds(
        (const __attribute__((address_space(1))) unsigned int*)g,
        (__attribute__((address_space(3))) unsigned int*)s, 16, 0, 0);
}

// ---------------------------------------------------------------------------
// pack_input: concat(gar,cond) fp32 [512][4096] -> inp_t bf16 in chunked
// layout [cc=16][pix=4096][32ch]  (64 B per pixel per cc-chunk).
// ---------------------------------------------------------------------------
__device__ void pack_input_dev(const float* __restrict__ gar,
                               const float* __restrict__ cond,
                               short* __restrict__ outp, int bx2, float* tile)
{
    int bx = bx2 & 127;                // px tile (128)
    int by = bx2 >> 7;                 // ch tile (16) == cc chunk
    int tx = threadIdx.x & 31;
    int ty = threadIdx.x >> 5;
#pragma unroll
    for (int i = 0; i < 4; ++i) {
        int c = by * 32 + ty + i * 8;
        const float* src = (c < 256) ? (gar + (size_t)c * HW)
                                     : (cond + (size_t)(c - 256) * HW);
        tile[(ty + i * 8) * 33 + tx] = src[bx * 32 + tx];
    }
    __syncthreads();
#pragma unroll
    for (int i = 0; i < 4; ++i) {
        int p = bx * 32 + ty + i * 8;
        outp[((size_t)by * 4096 + p) * 32 + tx] = f2bs(tile[tx * 33 + ty + i * 8]);
    }
}

// ---------------------------------------------------------------------------
// pack_w: W fp32 [G][CREAL][CIN][3][3] -> bf16 blocks.
// COAL=false (conv2-4): [g][nt][cc][tap 9][q 4][oc BN][8 ic]   (old layout)
// COAL=true  (conv1)  : [g][nt][cc][tap 9][oc BN][q 4][8 ic]   -> a wave's
//   64-lane weight-fragment load is one contiguous 1 KB span.
// BLKB = 9*4*BN*16 bytes either way.
// ---------------------------------------------------------------------------
template<int CIN, int CREAL, int BN, int NT, bool COAL>
__device__ void pack_w_dev(const float* __restrict__ wgt, char* __restrict__ wp,
                           int bx, short* sT)
{
    constexpr int NCC  = CIN / 32;
    constexpr int BLKB = 9 * 4 * BN * 16;

    const int t  = threadIdx.x;
    const int cc = bx % NCC;
    const int nt = (bx / NCC) % NT;
    const int g  = bx / (NT * NCC);

    for (int i = t; i < BLKB / 8; i += 256)
        reinterpret_cast<s16x4*>(sT)[i] = s16x4{0, 0, 0, 0};
    __syncthreads();

    int ocmax = CREAL - nt * BN; if (ocmax > BN) ocmax = BN;
    const size_t base = ((size_t)(g * CREAL + nt * BN) * CIN + cc * 32) * 9;
    for (int i = t; i < ocmax * 288; i += 256) {
        int oc = i / 288;
        int r  = i % 288;                      // ic*9 + tap
        int ic = r / 9, tap = r % 9;
        size_t idx;
        if (COAL) idx = (size_t)(((tap * BN + oc) * 4 + (ic >> 3)) * 8 + (ic & 7));
        else      idx = (size_t)(((tap * 4 + (ic >> 3)) * BN + oc) * 8 + (ic & 7));
        sT[idx] = f2bs(wgt[base + (size_t)oc * CIN * 9 + r]);
    }
    __syncthreads();

    const s16x4* src = reinterpret_cast<const s16x4*>(sT);
    s16x4* dst = reinterpret_cast<s16x4*>(wp + (size_t)bx * BLKB);
    for (int i = t; i < BLKB / 8; i += 256)
        dst[i] = src[i];
}

// All packing in one launch (block-range dispatch; branch is block-uniform).
__global__ __launch_bounds__(256)
void pack_all(const float* __restrict__ gar, const float* __restrict__ cond,
              const float* __restrict__ W1, const float* __restrict__ W2,
              const float* __restrict__ W3, const float* __restrict__ W4,
              short* inp_t, char* W1p, char* W2p, char* W3p, char* W4p)
{
    __shared__ __align__(16) short sbuf[9 * 4 * 64 * 8];   // 36864 B
    int bx = blockIdx.x;
    if (bx < 256)      pack_w_dev<512, 128, 64, 2, true >(W1, W1p, bx,       sbuf);
    else if (bx < 288) pack_w_dev<128,  64, 64, 1, false>(W2, W2p, bx - 256, sbuf);
    else if (bx < 304) pack_w_dev< 64,  32, 32, 1, false>(W3, W3p, bx - 288, sbuf);
    else if (bx < 312) pack_w_dev< 32,  18, 32, 1, false>(W4, W4p, bx - 304, sbuf);
    else pack_input_dev(gar, cond, inp_t, bx - 312, (float*)sbuf);
}

// ---------------------------------------------------------------------------
// Implicit-GEMM 3x3 SAME conv, bf16 MFMA 16x16x32, conflict-free LDS.
// (old template — still used for conv2/3/4; input layout [pix][ICP])
// ---------------------------------------------------------------------------
template<int ICP, int CREAL, int BN, int ROWS, int OF, int NT, int NW, int PIPE,
         bool PIXMAJ_OUT, bool LEAKY, bool OUT_F32>
__global__ __launch_bounds__(NW * 64, 2)
void conv_mfma(const short* __restrict__ inp, const char* __restrict__ wp,
               const float* __restrict__ bias, void* __restrict__ outv)
{
    constexpr int NCC  = ICP / 32;
    constexpr int HALO = ROWS + 2;
    constexpr int NPT  = 4096 / (ROWS * 64);
    constexpr int BLKB = 9 * 4 * BN * 16;
    constexpr int RNDS = BLKB / 1024;
    constexpr int NBUF = (PIPE && NCC > 1) ? 2 : 1;
    constexpr int SMAX = (HALO + NW - 1) / NW;

    __shared__ __align__(16) short sA[HALO][4][68][8];
    __shared__ __align__(16) char  sBraw[NBUF][BLKB];

    const int b  = blockIdx.x;
    const int g  = b & 7;                     // XCD swizzle: group per XCD
    const int r_ = b >> 3;
    const int pt = r_ % NPT;
    const int nt = r_ / NPT;
    const int r0 = pt * ROWS;

    const int t    = threadIdx.x;
    const int wave = t >> 6, lane = t & 63;
    const int l15  = lane & 15, quad = lane >> 4;

    int row_l, ocw;
    if (NW == 8) {
        if (ROWS == 4) { row_l = wave >> 1; ocw = (wave & 1) * (BN / 2); }
        else           { row_l = wave >> 2; ocw = (wave & 3) * (BN / 4); }
    } else {
        row_l = (ROWS == 4) ? wave : (wave & 1);
        ocw   = (ROWS == 4) ? 0 : (wave >> 1) * (BN / 2);
    }

    const size_t gpix = (ICP == 512) ? 0 : ((size_t)g * 4096);
    const char*  wb   = wp + (size_t)((g * NT + nt) * NCC) * BLKB;

    // sA staging: thread -> (col, row-slice); rows j = r2, r2+NW, ...
    const int acol = t & 63;
    const int r2   = t >> 6;

    bf16x8 pre[SMAX][4];

    auto stageA_load = [&](int cc) {
#pragma unroll
        for (int s = 0; s < SMAX; ++s) {
            int j = r2 + s * NW;
            if (j < HALO) {
                int gy = r0 - 1 + j;
                if (gy >= 0 && gy < 64) {
                    const short* sp = inp + ((gpix + gy * 64 + acol) * ICP + cc * 32);
#pragma unroll
                    for (int q = 0; q < 4; ++q)
                        pre[s][q] = *reinterpret_cast<const bf16x8*>(sp + q * 8);
                } else {
#pragma unroll
                    for (int q = 0; q < 4; ++q)
                        pre[s][q] = bf16x8{0, 0, 0, 0, 0, 0, 0, 0};
                }
            }
        }
    };
    auto stageA_write = [&]() {
#pragma unroll
        for (int s = 0; s < SMAX; ++s) {
            int j = r2 + s * NW;
            if (j < HALO) {
#pragma unroll
                for (int q = 0; q < 4; ++q)
                    *reinterpret_cast<bf16x8*>(&sA[j][q][acol + 1][0]) = pre[s][q];
            }
        }
    };
    auto stageB = [&](int cc) {
        const char* wsrc = wb + (size_t)cc * BLKB;
        char* sbb = (char*)sBraw[(NBUF == 2) ? (cc & 1) : 0];
        for (int r = wave; r < RNDS; r += NW)
            gl_lds16(wsrc + r * 1024 + lane * 16, sbb + r * 1024);
    };

    f32x4 acc[OF][4];
#pragma unroll
    for (int o = 0; o < OF; ++o)
#pragma unroll
        for (int p = 0; p < 4; ++p)
#pragma unroll
            for (int r = 0; r < 4; ++r) acc[o][p][r] = 0.f;

    // zero the x-pad column units (col index 0 and 65) once
    if (t < HALO * 8) {
        int row = t >> 3, q = (t >> 1) & 3, cp = (t & 1) ? 65 : 0;
        *reinterpret_cast<bf16x8*>(&sA[row][q][cp][0]) =
            bf16x8{0, 0, 0, 0, 0, 0, 0, 0};
    }

    // prologue: stage phase 0
    stageB(0);
    stageA_load(0);
    stageA_write();

    for (int cc = 0; cc < NCC; ++cc) {
        __syncthreads();               // sB(cc) drained, sA(cc) visible
        if (cc + 1 < NCC) {
            if (PIPE) stageB(cc + 1);  // dbuf: DMA into alternate buffer now
            stageA_load(cc + 1);       // global -> regs, no LDS touch
        }
        const bf16x8* sBv = reinterpret_cast<const bf16x8*>(
            sBraw[(NBUF == 2) ? (cc & 1) : 0]);

#pragma unroll
        for (int dy = 0; dy < 3; ++dy) {
#pragma unroll
            for (int dx = 0; dx < 3; ++dx) {
                bf16x8 pF[4];
#pragma unroll
                for (int p = 0; p < 4; ++p)
                    pF[p] = *reinterpret_cast<const bf16x8*>(
                        &sA[row_l + dy][quad][p * 16 + l15 + dx][0]);
                bf16x8 wF[OF];
#pragma unroll
                for (int o = 0; o < OF; ++o)
                    wF[o] = sBv[((dy * 3 + dx) * 4 + quad) * BN + ocw + o * 16 + l15];
#pragma unroll
                for (int o = 0; o < OF; ++o)
#pragma unroll
                    for (int p = 0; p < 4; ++p)
                        acc[o][p] = __builtin_amdgcn_mfma_f32_16x16x32_bf16(
                            wF[o], pF[p], acc[o][p], 0, 0, 0);
            }
        }
        __syncthreads();               // all reads of sA(cc)/sB(cc) done
        if (cc + 1 < NCC) {
            if (!PIPE) stageB(cc + 1); // single-buf: DMA into the freed buffer
            stageA_write();
        }
    }

    // ---- epilogue. C/D: m(oc) = quad*4+reg, n(pixel) = l15.
    const int prow = r0 + row_l;
#pragma unroll
    for (int o = 0; o < OF; ++o)
#pragma unroll
        for (int reg = 0; reg < 4; ++reg) {
            const int ocl = ocw + o * 16 + quad * 4 + reg;
            const int ocg = nt * BN + ocl;
            if (ocg < CREAL) {
                const float bv = bias[g * CREAL + ocg];
                if (PIXMAJ_OUT) {
                    short* outp = (short*)outv;
                    const size_t pixbase = ((size_t)g * 4096 + prow * 64);
#pragma unroll
                    for (int p = 0; p < 4; ++p) {
                        float v = acc[o][p][reg] + bv;
                        if (LEAKY) v = v >= 0.f ? v : 0.1f * v;
                        outp[(pixbase + p * 16 + l15) * (NT * BN) + ocg] = f2bs(v);
                    }
                } else if (OUT_F32) {
                    float* outp = (float*)outv;
                    const size_t base = ((size_t)(g * CREAL + ocg)) * HW + prow * IMG_W;
#pragma unroll
                    for (int p = 0; p < 4; ++p) {
                        float v = acc[o][p][reg] + bv;
                        if (LEAKY) v = v >= 0.f ? v : 0.1f * v;
                        outp[base + p * 16 + l15] = v;
                    }
                } else {
                    short* outp = (short*)outv;
                    const size_t base = ((size_t)(g * CREAL + ocg)) * HW + prow * IMG_W;
#pragma unroll
                    for (int p = 0; p < 4; ++p) {
                        float v = acc[o][p][reg] + bv;
                        if (LEAKY) v = v >= 0.f ? v : 0.1f * v;
                        outp[base + p * 16 + l15] = f2bs(v);
                    }
                }
            }
        }
}

// ---------------------------------------------------------------------------
// conv1_p2: dual-stream register pipeline, full-K, direct bf16 out.
// Round-5 evidence: per-cc pipes are now comparable (MFMA ~2.8K cyc,
// weight-L1 ~2.3K, LDS ~3.5K per CU) but still mostly serialized because
// only the weight stream was prefetched; the pF ds_reads had zero slack
// (sched_barrier even blocked the compiler from hoisting them).
// This kernel prefetches BOTH streams one tap ahead into alternating
// static register buffers:
//   tap: { issue pf[next] (4 ds_read), issue w[next] (2 global),
//          sched_barrier(0), 8 MFMA on pf[cur]/w[cur] }
// -> each load gets a full MFMA cluster of slack; one exposed pF latency
// per cc (tap0 primed right after the barrier).
// Geometry: ROWS=2, 8 waves = row(2) x ocq(4), OF=2 (32 oc/wave) -> per-CU
// weight-L1 traffic 144 KB/cc (half of r4). Full K (NCC=16) per block ->
// bf16+bias+leaky written directly, NO finalize kernel, NO fp32 partials.
// Grid 256 = 32 pt x 8 g, 1 block/CU, 8 waves/CU. LDS 33 KB dbuf,
// one barrier per cc (dbuf makes the second barrier unnecessary: a wave
// can only re-target buffer `cur` after ALL waves passed the next barrier,
// which they reach only after finishing this cc's reads).
// ---------------------------------------------------------------------------
__global__ __launch_bounds__(512, 2)
void conv1_p2(const short* __restrict__ inp, const char* __restrict__ wp,
              const float* __restrict__ bias, short* __restrict__ outp)
{
    __shared__ __align__(16) short sA[2][4][66][4][8];   // 33792 B

    const int b  = blockIdx.x;
    const int g  = b & 7;                     // XCD swizzle: group per XCD
    const int pt = b >> 3;                    // 0..31
    const int r0 = pt * 2;

    const int t    = threadIdx.x;
    const int wave = t >> 6, lane = t & 63;
    const int l15  = lane & 15, quad = lane >> 4;

    const int row_l = wave & 1;               // px row (0-1)
    const int ocq   = wave >> 1;              // oc quarter (0-3)
    const int ntw   = ocq >> 1;               // W1p nt half
    const int ocw64 = (ocq & 1) * 32;         // oc base within nt

    // W1p layout [g][nt][cc 16][tap 9][oc 64][q 4][ic 8]
    const short* wb    = (const short*)wp + (size_t)(g * 2 + ntw) * 16 * 18432;
    const short* wlane = wb + ((size_t)(ocw64 + l15) * 4 + quad) * 8;

    // staging: wave w -> halo row (w>>1), column half (w&1): 2 x 1KB DMA
    auto stageDMA = [&](int cc, int buf) {
        const int row = wave >> 1;
        const int gy  = r0 - 1 + row;
        if (gy >= 0 && gy < 64) {
            const short* src = inp + ((size_t)cc * 4096 + (size_t)gy * 64) * 32
                                   + (size_t)lane * 8;
            const int c4 = (wave & 1) * 2;
            gl_lds16(src + c4 * 512,       &sA[buf][row][1 + c4 * 16][0][0]);
            gl_lds16(src + (c4 + 1) * 512, &sA[buf][row][1 + (c4 + 1) * 16][0][0]);
        }
    };

    f32x4 acc[2][4];
#pragma unroll
    for (int o = 0; o < 2; ++o)
#pragma unroll
        for (int f = 0; f < 4; ++f)
#pragma unroll
            for (int r = 0; r < 4; ++r) acc[o][f][r] = 0.f;

    // prologue: DMA(0) into buf0, zero x-pads (both bufs) + OOB rows
    stageDMA(0, 0);
    if (t < 64) {
        int buf = t >> 5, row = (t >> 3) & 3, q = (t >> 1) & 3;
        int col = (t & 1) ? 65 : 0;
        *reinterpret_cast<bf16x8*>(&sA[buf][row][col][q][0]) =
            bf16x8{0, 0, 0, 0, 0, 0, 0, 0};
    }
    if (r0 == 0 || r0 == 62) {
        int zr = (r0 == 0) ? 0 : 3;           // gy=-1 or gy=64: zero forever
        for (int i = t; i < 2 * 66 * 4; i += 512) {
            int buf = i / 264, rem = i % 264;
            *reinterpret_cast<bf16x8*>(&sA[buf][zr][rem >> 2][rem & 3][0]) =
                bf16x8{0, 0, 0, 0, 0, 0, 0, 0};
        }
    }

    // weight double-buffer (16 VGPR) + pF double-buffer (32 VGPR)
    bf16x8 w[2][2];
    bf16x8 pf[2][4];
#pragma unroll
    for (int o = 0; o < 2; ++o)               // cc0 tap0 weights -> w[0]
        w[0][o] = *reinterpret_cast<const bf16x8*>(wlane + o * 512);

    auto body = [&](int cc, int cur, int par) {
        const short* wcc = wlane + (size_t)cc * 18432;
        __syncthreads();                      // sA[cur] published (DMA drained)
        if (cc + 1 < 16) stageDMA(cc + 1, cur ^ 1);
        // prime tap0 pF
#pragma unroll
        for (int f = 0; f < 4; ++f)
            pf[0][f] = *reinterpret_cast<const bf16x8*>(
                &sA[cur][row_l][f * 16 + l15][quad][0]);
#pragma unroll
        for (int tap = 0; tap < 9; ++tap) {
            const int pb = tap & 1, pn = pb ^ 1;
            const int cb = (tap + par) & 1, nb = cb ^ 1;
            // prefetch next tap's pF (taps 0-7; tap8's next comes after barrier)
            if (tap < 8) {
                const int dy1 = (tap + 1) / 3, dx1 = (tap + 1) % 3;
#pragma unroll
                for (int f = 0; f < 4; ++f)
                    pf[pn][f] = *reinterpret_cast<const bf16x8*>(
                        &sA[cur][row_l + dy1][f * 16 + l15 + dx1][quad][0]);
            }
            // prefetch next tap's weights (tap8 -> next cc's tap0 by layout;
            // last cc's overread = 1KB of dead workspace, never used)
            const short* nsrc = wcc + (size_t)(tap + 1) * 2048;
#pragma unroll
            for (int o = 0; o < 2; ++o)
                w[nb][o] = *reinterpret_cast<const bf16x8*>(nsrc + o * 512);
            __builtin_amdgcn_sched_barrier(0);   // pin both streams pre-MFMA
#pragma unroll
            for (int o = 0; o < 2; ++o)
#pragma unroll
                for (int f = 0; f < 4; ++f)
                    acc[o][f] = __builtin_amdgcn_mfma_f32_16x16x32_bf16(
                        w[cb][o], pf[pb][f], acc[o][f], 0, 0, 0);
        }
    };

    // 9 taps flip the w parity each cc: par = cc & 1; cur = cc & 1.
    for (int c2 = 0; c2 < 16; c2 += 2) {
        body(c2,     0, 0);
        body(c2 + 1, 1, 1);
    }

    // epilogue: bias + leaky -> bf16, out [pix][128]. m(oc)=quad*4+reg.
    const int prow = r0 + row_l;
    const size_t pixbase = (size_t)g * 4096 + (size_t)prow * 64;
#pragma unroll
    for (int o = 0; o < 2; ++o)
#pragma unroll
        for (int reg = 0; reg < 4; ++reg) {
            const int ocg = ocq * 32 + o * 16 + quad * 4 + reg;
            const float bv = bias[g * 128 + ocg];
#pragma unroll
            for (int f = 0; f < 4; ++f) {
                float v = acc[o][f][reg] + bv;
                v = v >= 0.f ? v : 0.1f * v;
                outp[(pixbase + f * 16 + l15) * 128 + ocg] = f2bs(v);
            }
        }
}

// ---------------------------------------------------------------------------
// Fused softmax-over-groups + bilinear params + warp + combine (fp32 out).
// gar channels come from inp_t chunks (layout [cc][4096][32], first 8 chunks).
// ---------------------------------------------------------------------------
__global__ __launch_bounds__(256)
void warp_combine_kernel(const float* __restrict__ oa,
                         const short* __restrict__ inp_t,
                         const float* __restrict__ mask,
                         float* __restrict__ out)
{
    __shared__ __align__(16) float4 sWts[8][6][8];
    __shared__ __align__(16) int4   sIdx[8][6][8];

    const int t = threadIdx.x;

    if (t < 48) {
        int lp = t / 6;
        int k  = t % 6;
        int p  = blockIdx.x * 8 + lp;
        int x  = p & 63, y = p >> 6;

        float l[8];
        float m = -1e30f;
#pragma unroll
        for (int g = 0; g < 8; ++g) {
            l[g] = oa[(size_t)(g * 18 + 12 + k) * HW + p];
            m = fmaxf(m, l[g]);
        }
        float s = 0.f;
#pragma unroll
        for (int g = 0; g < 8; ++g) { l[g] = __expf(l[g] - m); s += l[g]; }
        float inv = 1.f / s;

#pragma unroll
        for (int g = 0; g < 8; ++g) {
            float a  = l[g] * inv;
            float ox = oa[(size_t)(g * 18 + 2 * k)     * HW + p];
            float oy = oa[(size_t)(g * 18 + 2 * k + 1) * HW + p];
            float sx = fminf(fmaxf(((float)x + ox) * (64.f / 63.f) - 0.5f, 0.f), 63.f);
            float sy = fminf(fmaxf(((float)y + oy) * (64.f / 63.f) - 0.5f, 0.f), 63.f);
            float fx0 = floorf(sx), fy0 = floorf(sy);
            int   x0 = (int)fx0,    y0i = (int)fy0;
            float wx = sx - fx0,    wy = sy - fy0;
            int   x1 = min(x0 + 1, 63), y1 = min(y0i + 1, 63);
            sWts[lp][k][g] = make_float4(a * (1.f - wy) * (1.f - wx),
                                         a * (1.f - wy) * wx,
                                         a * wy * (1.f - wx),
                                         a * wy * wx);
            sIdx[lp][k][g] = make_int4(y0i * 64 + x0, y0i * 64 + x1,
                                       y1  * 64 + x0, y1  * 64 + x1);
        }
    }
    __syncthreads();

    const int lp = t >> 5;
    const int p  = blockIdx.x * 8 + lp;
    const int c0 = (t & 31) * 8;
    const short* ipc = inp_t + (size_t)(c0 >> 5) * (4096 * 32) + (c0 & 31);

    float acc[8];
#pragma unroll
    for (int j = 0; j < 8; ++j) acc[j] = 0.f;

    for (int g = 0; g < 8; ++g) {
        float4 m0 = *reinterpret_cast<const float4*>(mask + g * 256 + c0);
        float4 m1 = *reinterpret_cast<const float4*>(mask + g * 256 + c0 + 4);
        float mk[8] = {m0.x, m0.y, m0.z, m0.w, m1.x, m1.y, m1.z, m1.w};
#pragma unroll
        for (int k = 0; k < 6; ++k) {
            float4 w  = sWts[lp][k][g];
            int4   id = sIdx[lp][k][g];
            ushort8v v00 = *reinterpret_cast<const ushort8v*>(ipc + (size_t)id.x * 32);
            ushort8v v01 = *reinterpret_cast<const ushort8v*>(ipc + (size_t)id.y * 32);
            ushort8v v10 = *reinterpret_cast<const ushort8v*>(ipc + (size_t)id.z * 32);
            ushort8v v11 = *reinterpret_cast<const ushort8v*>(ipc + (size_t)id.w * 32);
#pragma unroll
            for (int j = 0; j < 8; ++j) {
                float sv = w.x * bfbits2f(v00[j]) + w.y * bfbits2f(v01[j])
                         + w.z * bfbits2f(v10[j]) + w.w * bfbits2f(v11[j]);
                acc[j] = fmaf(mk[j], sv, acc[j]);
            }
        }
    }
#pragma unroll
    for (int j = 0; j < 8; ++j)
        out[(size_t)(c0 + j) * HW + p] = acc[j];
}

// ---------------------------------------------------------------------------
// Workspace: old layout (peak ~25 MB); k-split partials no longer needed.
// ---------------------------------------------------------------------------
extern "C" void kernel_launch(void* const* d_in, const int* in_sizes, int n_in,
                              void* d_out, int out_size, void* d_ws, size_t ws_size,
                              hipStream_t stream)
{
    (void)in_sizes; (void)n_in; (void)out_size; (void)ws_size;
    const float* gar  = (const float*)d_in[0];
    const float* cond = (const float*)d_in[1];
    const float* mask = (const float*)d_in[2];
    const float* W1   = (const float*)d_in[3];
    const float* b1   = (const float*)d_in[4];
    const float* W2   = (const float*)d_in[5];
    const float* b2   = (const float*)d_in[6];
    const float* W3   = (const float*)d_in[7];
    const float* b3   = (const float*)d_in[8];
    const float* W4   = (const float*)d_in[9];
    const float* b4   = (const float*)d_in[10];
    float* out = (float*)d_out;

    char* ws = (char*)d_ws;
    short* inp_t  = (short*)(ws);
    char*  W1p    = ws + (4u << 20);
    short* hid2_t = (short*)(ws + (4u << 20));          // overlays dead W1p
    short* hid3_t = (short*)(ws + (8u << 20));          // overlays dead W1p
    float* oa     = (float*)(ws + (10u << 20) + (512u << 10));
    char*  W2p    = ws + (14u << 20);
    char*  W3p    = ws + (15u << 20) + (512u << 10);
    char*  W4p    = ws + (16u << 20);
    short* hid1_t = (short*)(ws + (17u << 20));

    // 312 weight-pack blocks + 2048 input-transpose blocks, one launch
    pack_all<<<2360, 256, 0, stream>>>(gar, cond, W1, W2, W3, W4,
                                       inp_t, W1p, W2p, W3p, W4p);

    // conv1: dual-stream pipelined, full-K, direct bf16 out (no finalize)
    conv1_p2<<<256, 512, 0, stream>>>(inp_t, W1p, b1, hid1_t);
    // conv2: 128->64, ROWS=2, BN=64, OF=1, NT=1, NW=8, PIPE=1 (unchanged)
    conv_mfma<128, 64, 64, 2, 1, 1, 8, 1, true, true, false>
        <<<256, 512, 0, stream>>>(hid1_t, W2p, b2, hid2_t);
    // conv3: 64->32, ROWS=2, BN=32, OF=1, NT=1, NW=4, PIPE=1 (unchanged)
    conv_mfma<64, 32, 32, 2, 1, 1, 4, 1, true, true, false>
        <<<256, 256, 0, stream>>>(hid2_t, W3p, b3, hid3_t);
    // conv4: 32->18 (pad 32), ROWS=2, BN=32, OF=1, NT=1, NW=4 (unchanged)
    conv_mfma<32, 18, 32, 2, 1, 1, 4, 1, false, false, true>
        <<<256, 256, 0, stream>>>(hid3_t, W4p, b4, oa);

    warp_combine_kernel<<<512, 256, 0, stream>>>(oa, inp_t, mask, out);
}